// Round 3
// baseline (155.369 us; speedup 1.0000x reference)
//
#include <hip/hip_runtime.h>
#include <stdint.h>

#define NB 32
#define NT 2000
#define NH 256
#define NS 63
#define LDSROW 264                         // padded bf16 row stride (528 B)
#define TILE_USHORTS (65 * LDSROW)         // one E/h/U tile region (34320 B)

typedef __attribute__((ext_vector_type(8))) short bf16x8;
typedef __attribute__((ext_vector_type(4))) float f32x4;

__device__ inline unsigned short f2bf(float f) {
  union { float f; uint32_t u; } v; v.f = f;
  return (unsigned short)((v.u + 0x7fffu + ((v.u >> 16) & 1u)) >> 16);  // RNE
}
__device__ inline unsigned int pk2(float a, float b) {
  return (unsigned int)f2bf(a) | ((unsigned int)f2bf(b) << 16);
}
__device__ inline bf16x8 pack8(const float* g) {
  union { bf16x8 v; unsigned int u[4]; } c;
  c.u[0] = pk2(g[0], g[1]); c.u[1] = pk2(g[2], g[3]);
  c.u[2] = pk2(g[4], g[5]); c.u[3] = pk2(g[6], g[7]);
  return c.v;
}

// Pre-packed MFMA B-fragment layouts (bf16), built once per launch in d_ws:
//   W1F: [km:16][w:4][tn:4][lane:64][j:8]  -> 16384 slots * 16 B = 256 KiB
//   W2F: [ks:8][tn:4][lane:64][j:8]        ->  2048 slots * 16 B =  32 KiB
#define NSLOT1 (16 * 4 * 4 * 64)
#define NSLOT2 (8 * 4 * 64)
#define WS_NEEDED ((size_t)(NSLOT1 + NSLOT2) * 16)

__global__ __launch_bounds__(256) void prep_weights(
    const float* __restrict__ W1, const float* __restrict__ W2,
    unsigned short* __restrict__ w1f, unsigned short* __restrict__ w2f) {
  const int tid = blockIdx.x * 256 + threadIdx.x;
  if (tid < NSLOT1) {
    const int lane = tid & 63;
    const int quad = lane >> 4, l16 = lane & 15;
    int r = tid >> 6;
    const int tn = r & 3; r >>= 2;
    const int wv = r & 3; r >>= 2;
    const int km = r;  // 0..15
    const int kb = (km >> 3) * 256 + (km & 7) * 32 + quad * 8;
    const int n = wv * 64 + tn * 16 + l16;
    ushort4 lo, hi;
    lo.x = f2bf(W1[(size_t)(kb + 0) * NH + n]);
    lo.y = f2bf(W1[(size_t)(kb + 1) * NH + n]);
    lo.z = f2bf(W1[(size_t)(kb + 2) * NH + n]);
    lo.w = f2bf(W1[(size_t)(kb + 3) * NH + n]);
    hi.x = f2bf(W1[(size_t)(kb + 4) * NH + n]);
    hi.y = f2bf(W1[(size_t)(kb + 5) * NH + n]);
    hi.z = f2bf(W1[(size_t)(kb + 6) * NH + n]);
    hi.w = f2bf(W1[(size_t)(kb + 7) * NH + n]);
    *(ushort4*)&w1f[(size_t)tid * 8] = lo;
    *(ushort4*)&w1f[(size_t)tid * 8 + 4] = hi;
  } else if (tid < NSLOT1 + NSLOT2) {
    const int t2 = tid - NSLOT1;
    const int lane = t2 & 63;
    const int quad = lane >> 4, l16 = lane & 15;
    const int tn = (t2 >> 6) & 3;
    const int ks = t2 >> 8;  // 0..7
    const int kb = ks * 32 + quad * 8;
    const int n = tn * 16 + l16;
    ushort4 lo = {0, 0, 0, 0}, hi = {0, 0, 0, 0};
    if (n < NS) {
      lo.x = f2bf(W2[(size_t)(kb + 0) * NS + n]);
      lo.y = f2bf(W2[(size_t)(kb + 1) * NS + n]);
      lo.z = f2bf(W2[(size_t)(kb + 2) * NS + n]);
      lo.w = f2bf(W2[(size_t)(kb + 3) * NS + n]);
      hi.x = f2bf(W2[(size_t)(kb + 4) * NS + n]);
      hi.y = f2bf(W2[(size_t)(kb + 5) * NS + n]);
      hi.z = f2bf(W2[(size_t)(kb + 6) * NS + n]);
      hi.w = f2bf(W2[(size_t)(kb + 7) * NS + n]);
    }
    *(ushort4*)&w2f[(size_t)t2 * 8] = lo;
    *(ushort4*)&w2f[(size_t)t2 * 8 + 4] = hi;
  }
}

// ---------------- device helpers (all force-inlined) ----------------

// Direct stage: 65 E rows (clamped), f32 -> bf16 -> LDS region R.
__device__ __forceinline__ void stage_direct(const float* __restrict__ Eb,
                                             unsigned short* R, int base,
                                             int tid, int w, int lane) {
  #pragma unroll
  for (int it = 0; it < 16; ++it) {
    const int row = it * 4 + w;
    int tr = base + row;
    tr = (tr < 0) ? 0 : (tr > NT - 1 ? NT - 1 : tr);
    float4 v = *(const float4*)&Eb[(size_t)tr * NH + (lane << 2)];
    ushort4 o;
    o.x = f2bf(v.x); o.y = f2bf(v.y); o.z = f2bf(v.z); o.w = f2bf(v.w);
    *(ushort4*)&R[row * LDSROW + (lane << 2)] = o;
  }
  if (tid < 64) {
    int tr = base + 64; if (tr > NT - 1) tr = NT - 1;
    float4 v = *(const float4*)&Eb[(size_t)tr * NH + (lane << 2)];
    ushort4 o;
    o.x = f2bf(v.x); o.y = f2bf(v.y); o.z = f2bf(v.z); o.w = f2bf(v.w);
    *(ushort4*)&R[64 * LDSROW + (lane << 2)] = o;
  }
}

// T14 issue-early half: load 65 E rows into registers (no LDS write yet).
__device__ __forceinline__ void prefetch_rows(const float* __restrict__ Eb,
                                              int base, int tid, int w, int lane,
                                              float4 eb[17]) {
  #pragma unroll
  for (int it = 0; it < 16; ++it) {
    const int row = it * 4 + w;
    int tr = base + row;
    tr = (tr < 0) ? 0 : (tr > NT - 1 ? NT - 1 : tr);
    eb[it] = *(const float4*)&Eb[(size_t)tr * NH + (lane << 2)];
  }
  if (tid < 64) {
    int tr = base + 64; if (tr > NT - 1) tr = NT - 1;
    eb[16] = *(const float4*)&Eb[(size_t)tr * NH + (lane << 2)];
  }
}

// T14 write-late half: convert held rows and store to LDS region R.
__device__ __forceinline__ void write_rows(unsigned short* R, int tid, int w,
                                           int lane, const float4 eb[17]) {
  #pragma unroll
  for (int it = 0; it < 16; ++it) {
    const int row = it * 4 + w;
    float4 v = eb[it];
    ushort4 o;
    o.x = f2bf(v.x); o.y = f2bf(v.y); o.z = f2bf(v.z); o.w = f2bf(v.w);
    *(ushort4*)&R[row * LDSROW + (lane << 2)] = o;
  }
  if (tid < 64) {
    float4 v = eb[16];
    ushort4 o;
    o.x = f2bf(v.x); o.y = f2bf(v.y); o.z = f2bf(v.z); o.w = f2bf(v.w);
    *(ushort4*)&R[64 * LDSROW + (lane << 2)] = o;
  }
}

__device__ __forceinline__ void gemm1_packed(
    const unsigned short* R, const unsigned short* __restrict__ w1f,
    int w, int lane, int quad, int l16, f32x4 acc[4][4]) {
  const unsigned short* wbase = w1f + (size_t)(((w << 2) * 64) + lane) * 8;
  bf16x8 cb0 = *(const bf16x8*)(wbase + ((size_t)0 << 9));
  bf16x8 cb1 = *(const bf16x8*)(wbase + ((size_t)1 << 9));
  bf16x8 cb2 = *(const bf16x8*)(wbase + ((size_t)2 << 9));
  bf16x8 cb3 = *(const bf16x8*)(wbase + ((size_t)3 << 9));
  #pragma unroll
  for (int km = 0; km < 16; ++km) {
    bf16x8 nb0, nb1, nb2, nb3;
    if (km < 15) {  // one-ahead register double buffer (hides L2 latency)
      nb0 = *(const bf16x8*)(wbase + ((size_t)(((km + 1) << 4) + 0) << 9));
      nb1 = *(const bf16x8*)(wbase + ((size_t)(((km + 1) << 4) + 1) << 9));
      nb2 = *(const bf16x8*)(wbase + ((size_t)(((km + 1) << 4) + 2) << 9));
      nb3 = *(const bf16x8*)(wbase + ((size_t)(((km + 1) << 4) + 3) << 9));
    }
    const int aoff = (km >> 3) ? 0 : 1;  // top half pairs e[t+1]
    bf16x8 af[4];
    #pragma unroll
    for (int tm = 0; tm < 4; ++tm)
      af[tm] = *(const bf16x8*)&R[(tm * 16 + l16 + aoff) * LDSROW +
                                  (km & 7) * 32 + quad * 8];
    #pragma unroll
    for (int tm = 0; tm < 4; ++tm)
      acc[tm][0] = __builtin_amdgcn_mfma_f32_16x16x32_bf16(af[tm], cb0, acc[tm][0], 0, 0, 0);
    #pragma unroll
    for (int tm = 0; tm < 4; ++tm)
      acc[tm][1] = __builtin_amdgcn_mfma_f32_16x16x32_bf16(af[tm], cb1, acc[tm][1], 0, 0, 0);
    #pragma unroll
    for (int tm = 0; tm < 4; ++tm)
      acc[tm][2] = __builtin_amdgcn_mfma_f32_16x16x32_bf16(af[tm], cb2, acc[tm][2], 0, 0, 0);
    #pragma unroll
    for (int tm = 0; tm < 4; ++tm)
      acc[tm][3] = __builtin_amdgcn_mfma_f32_16x16x32_bf16(af[tm], cb3, acc[tm][3], 0, 0, 0);
    if (km < 15) { cb0 = nb0; cb1 = nb1; cb2 = nb2; cb3 = nb3; }
  }
}

__device__ __forceinline__ void gemm1_gather(
    const unsigned short* R, const float* __restrict__ W1,
    int w, int lane, int quad, int l16, f32x4 acc[4][4]) {
  const int n0 = w * 64;
  const float* w1p = W1 + (size_t)(quad * 8) * NH + n0 + l16;
  #pragma unroll
  for (int km = 0; km < 16; ++km) {
    const int hk = (km >> 3) * 256 + (km & 7) * 32;
    const int aoff = (km >> 3) ? 0 : 1;
    bf16x8 af[4];
    #pragma unroll
    for (int tm = 0; tm < 4; ++tm)
      af[tm] = *(const bf16x8*)&R[(tm * 16 + l16 + aoff) * LDSROW +
                                  (km & 7) * 32 + quad * 8];
    float g[8], gn[8];
    #pragma unroll
    for (int j = 0; j < 8; ++j) g[j] = w1p[(size_t)(hk + j) * NH];
    #pragma unroll
    for (int tn = 0; tn < 4; ++tn) {
      if (tn < 3) {
        #pragma unroll
        for (int j = 0; j < 8; ++j)
          gn[j] = w1p[(size_t)(hk + j) * NH + (tn + 1) * 16];
      }
      bf16x8 bq = pack8(g);
      #pragma unroll
      for (int tm = 0; tm < 4; ++tm)
        acc[tm][tn] = __builtin_amdgcn_mfma_f32_16x16x32_bf16(
            af[tm], bq, acc[tm][tn], 0, 0, 0);
      if (tn < 3) {
        #pragma unroll
        for (int j = 0; j < 8; ++j) g[j] = gn[j];
      }
    }
  }
}

__device__ __forceinline__ void write_h(unsigned short* R, const float* __restrict__ b1,
                                        int w, int quad, int l16,
                                        const f32x4 acc[4][4]) {
  const int n0 = w * 64;
  #pragma unroll
  for (int tn = 0; tn < 4; ++tn) {
    float b1v = b1[n0 + tn * 16 + l16];
    #pragma unroll
    for (int tm = 0; tm < 4; ++tm)
      #pragma unroll
      for (int r = 0; r < 4; ++r) {
        float hv = fmaxf(acc[tm][tn][r] + b1v, 0.f);
        R[(tm * 16 + quad * 4 + r) * LDSROW + n0 + tn * 16 + l16] = f2bf(hv);
      }
  }
}

__device__ __forceinline__ void prefetch_lpv(const float* __restrict__ lb,
                                             int a0, int m0, int quad, int l16,
                                             float lpv[16]) {
  #pragma unroll
  for (int tn = 0; tn < 4; ++tn) {
    const int s = tn * 16 + l16;
    const int cc = (s < NS) ? s : NS - 1;
    #pragma unroll
    for (int r = 0; r < 4; ++r) {
      int tt = a0 + m0 + quad * 4 + r;
      if (tt > NT - 1) tt = NT - 1;
      lpv[tn * 4 + r] = lb[(size_t)tt * NS + cc];
    }
  }
}

__device__ __forceinline__ void gemm2_packed(
    const unsigned short* R, const unsigned short* __restrict__ w2f,
    int w, int lane, int quad, int l16, f32x4 acc2[4]) {
  const int m0 = w * 16;
  const unsigned short* w2base = w2f + (size_t)lane * 8;
  #pragma unroll
  for (int ks = 0; ks < 8; ++ks) {
    bf16x8 af = *(const bf16x8*)&R[(m0 + l16) * LDSROW + ks * 32 + quad * 8];
    #pragma unroll
    for (int tn = 0; tn < 4; ++tn) {
      bf16x8 bq = *(const bf16x8*)(w2base + ((size_t)((ks << 2) + tn) << 9));
      acc2[tn] = __builtin_amdgcn_mfma_f32_16x16x32_bf16(af, bq, acc2[tn], 0, 0, 0);
    }
  }
}

__device__ __forceinline__ void gemm2_gather(
    const unsigned short* R, const float* __restrict__ W2,
    int w, int lane, int quad, int l16, f32x4 acc2[4]) {
  const int m0 = w * 16;
  #pragma unroll
  for (int ks = 0; ks < 8; ++ks) {
    const int k0 = ks * 32;
    bf16x8 af = *(const bf16x8*)&R[(m0 + l16) * LDSROW + k0 + quad * 8];
    #pragma unroll
    for (int tn = 0; tn < 4; ++tn) {
      const int n = tn * 16 + l16;
      float g[8];
      #pragma unroll
      for (int j = 0; j < 8; ++j)
        g[j] = (n < NS) ? W2[(size_t)(k0 + quad * 8 + j) * NS + n] : 0.f;
      bf16x8 bq = pack8(g);
      acc2[tn] = __builtin_amdgcn_mfma_f32_16x16x32_bf16(af, bq, acc2[tn], 0, 0, 0);
    }
  }
}

// U[m][s] = trans[base+m][s] + b2[s] + logits[a0+m][s]
__device__ __forceinline__ void write_U(float* TRf, const float* __restrict__ b2,
                                        const float lpv[16], int m0, int quad,
                                        int l16, const f32x4 acc2[4]) {
  #pragma unroll
  for (int tn = 0; tn < 4; ++tn) {
    const int s = tn * 16 + l16;
    const float b2v = (s < NS) ? b2[s] : 0.f;
    #pragma unroll
    for (int r = 0; r < 4; ++r)
      TRf[(m0 + quad * 4 + r) * 68 + s] = acc2[tn][r] + b2v + lpv[tn * 4 + r];
  }
}

// Softmax for t = a0 + j, j in [0, 62]: sc = U[j] + U[j+1] (interior)
__device__ __forceinline__ void softmax_store(const float* TRf,
    const float* __restrict__ lb, const int* __restrict__ kw,
    float* __restrict__ out, int b, int a0, int m0, int lane) {
  for (int rr = 0; rr < 16; ++rr) {
    const int j = m0 + rr;
    const int t = a0 + j;
    if (j == 63 || t > NT - 1) continue;
    float sc;
    if (t == 0) {
      float v = (lane < NS) ? lb[lane] : -1e30f;  // logits row 0 from global
      float m = v;
      #pragma unroll
      for (int o = 32; o > 0; o >>= 1) m = fmaxf(m, __shfl_xor(m, o));
      float ee = (lane < NS) ? __expf(v - m) : 0.f;
      float ss = ee;
      #pragma unroll
      for (int o = 32; o > 0; o >>= 1) ss += __shfl_xor(ss, o);
      const float lse = m + __logf(ss);
      const float f00 = lb[kw[b * 32]] - lse;
      sc = ((lane == 0) ? f00 : 0.f) + TRf[68 + lane];  // + U[1]
    } else if (t == NT - 1) {
      sc = TRf[j * 68 + lane];                          // U[j]
    } else {
      sc = TRf[j * 68 + lane] + TRf[(j + 1) * 68 + lane];
    }
    float e = (lane < NS) ? __expf(sc) : 0.f;
    float s = e;
    #pragma unroll
    for (int o = 32; o > 0; o >>= 1) s += __shfl_xor(s, o);
    if (lane < NS) out[((size_t)b * NT + t) * NS + lane] = e / s;
  }
}

// ---------------- main kernel: 2-tile software pipeline ----------------
// 512 blocks (16 pairs x 32 batches), 2 blocks/CU (dynamic LDS 68640 B).
// Tile A = 2i, tile B = 2i+1 (63 t's each, proven 64-row MFMA geometry).
// Pipeline: E_B loads issued just before GEMM1_A's MFMAs (latency hides
// under MFMA), written to R2 after the E_A-reads barrier (T14 split);
// softmax_A runs after GEMM1_B (independent LDS regions) so tile-A VALU
// overlaps tile-B MFMA across waves.
template <bool PACKED>
__global__ __launch_bounds__(256, 2) void fused_kernel(
    const float* __restrict__ E, const float* __restrict__ logits,
    const int* __restrict__ kw,
    const float* __restrict__ W1, const float* __restrict__ W2,
    const unsigned short* __restrict__ w1f, const unsigned short* __restrict__ w2f,
    const float* __restrict__ b1, const float* __restrict__ b2,
    float* __restrict__ out) {
  const int b = blockIdx.y;
  const int a0A = blockIdx.x * 126;   // tile A first align t
  const int a0B = a0A + 63;           // tile B first align t
  const int tid = threadIdx.x;
  const int w = tid >> 6;
  const int lane = tid & 63;
  const int quad = lane >> 4;
  const int l16 = lane & 15;
  const int m0 = w * 16;

  extern __shared__ unsigned short lds[];          // 2 * TILE_USHORTS
  unsigned short* R1 = lds;                        // E_A -> h -> U (both tiles)
  unsigned short* R2 = lds + TILE_USHORTS;         // E_B
  float* TRf = (float*)lds;                        // U[64][68] f32 in R1

  const float* Eb = E + (size_t)b * NT * NH;
  const float* lb = logits + (size_t)b * NT * NS;

  // ---- Phase 0: stage E_A -> R1 ----
  stage_direct(Eb, R1, a0A - 1, tid, w, lane);
  __syncthreads();

  // ---- Phase 1: issue E_B loads (regs), then GEMM1_A (HBM hides under MFMA) ----
  float4 eb[17];
  prefetch_rows(Eb, a0B - 1, tid, w, lane, eb);

  f32x4 acc[4][4];
  #pragma unroll
  for (int tm = 0; tm < 4; ++tm)
    #pragma unroll
    for (int tn = 0; tn < 4; ++tn) acc[tm][tn] = (f32x4){0.f, 0.f, 0.f, 0.f};
  if constexpr (PACKED) gemm1_packed(R1, w1f, w, lane, quad, l16, acc);
  else                  gemm1_gather(R1, W1, w, lane, quad, l16, acc);
  __syncthreads();  // E_A reads done

  // ---- Phase 2: E_B regs -> R2 ; h_A -> R1 ----
  write_rows(R2, tid, w, lane, eb);
  write_h(R1, b1, w, quad, l16, acc);
  __syncthreads();

  // ---- Phase 3: lpv_A prefetch, GEMM2_A ----
  float lpvA[16];
  prefetch_lpv(lb, a0A, m0, quad, l16, lpvA);
  f32x4 acc2[4];
  #pragma unroll
  for (int tn = 0; tn < 4; ++tn) acc2[tn] = (f32x4){0.f, 0.f, 0.f, 0.f};
  if constexpr (PACKED) gemm2_packed(R1, w2f, w, lane, quad, l16, acc2);
  else                  gemm2_gather(R1, W2, w, lane, quad, l16, acc2);
  __syncthreads();  // h_A reads done

  // ---- Phase 4: U_A -> R1 ----
  write_U(TRf, b2, lpvA, m0, quad, l16, acc2);
  __syncthreads();

  // ---- Phase 5: lpv_B, GEMM1_B (reads R2), then softmax_A (reads R1-U) ----
  float lpvB[16];
  prefetch_lpv(lb, a0B, m0, quad, l16, lpvB);
  #pragma unroll
  for (int tm = 0; tm < 4; ++tm)
    #pragma unroll
    for (int tn = 0; tn < 4; ++tn) acc[tm][tn] = (f32x4){0.f, 0.f, 0.f, 0.f};
  if constexpr (PACKED) gemm1_packed(R2, w1f, w, lane, quad, l16, acc);
  else                  gemm1_gather(R2, W1, w, lane, quad, l16, acc);
  softmax_store(TRf, lb, kw, out, b, a0A, m0, lane);
  __syncthreads();  // U_A reads + E_B reads done

  // ---- Phase 6: h_B -> R1 ----
  write_h(R1, b1, w, quad, l16, acc);
  __syncthreads();

  // ---- Phase 7: GEMM2_B ----
  #pragma unroll
  for (int tn = 0; tn < 4; ++tn) acc2[tn] = (f32x4){0.f, 0.f, 0.f, 0.f};
  if constexpr (PACKED) gemm2_packed(R1, w2f, w, lane, quad, l16, acc2);
  else                  gemm2_gather(R1, W2, w, lane, quad, l16, acc2);
  __syncthreads();  // h_B reads done

  // ---- Phase 8: U_B -> R1 ----
  write_U(TRf, b2, lpvB, m0, quad, l16, acc2);
  __syncthreads();

  // ---- Phase 9: softmax_B ----
  softmax_store(TRf, lb, kw, out, b, a0B, m0, lane);
}

extern "C" void kernel_launch(void* const* d_in, const int* in_sizes, int n_in,
                              void* d_out, int out_size, void* d_ws, size_t ws_size,
                              hipStream_t stream) {
  const float* logits = (const float*)d_in[0];
  const float* E      = (const float*)d_in[1];
  const int*   kw     = (const int*)d_in[2];
  const float* W1     = (const float*)d_in[3];
  const float* b1     = (const float*)d_in[4];
  const float* W2     = (const float*)d_in[5];
  const float* b2     = (const float*)d_in[6];
  float* out = (float*)d_out;

  dim3 g(16, NB);  // 16 tile-pairs (126 t's each) x 32 batches = 512 blocks
  const size_t shmem = (size_t)2 * TILE_USHORTS * sizeof(unsigned short);  // 68640

  if (ws_size >= WS_NEEDED && d_ws != nullptr) {
    unsigned short* w1f = (unsigned short*)d_ws;
    unsigned short* w2f = w1f + (size_t)NSLOT1 * 8;
    prep_weights<<<dim3((NSLOT1 + NSLOT2) / 256), 256, 0, stream>>>(W1, W2, w1f, w2f);
    fused_kernel<true><<<g, 256, shmem, stream>>>(E, logits, kw, W1, W2, w1f, w2f,
                                                  b1, b2, out);
  } else {
    fused_kernel<false><<<g, 256, shmem, stream>>>(E, logits, kw, W1, W2, nullptr,
                                                   nullptr, b1, b2, out);
  }
}

// Round 4
// 137.214 us; speedup vs baseline: 1.1323x; 1.1323x over previous
//
#include <hip/hip_runtime.h>
#include <stdint.h>

#define NB 32
#define NT 2000
#define NH 256
#define NS 63
#define LDSROW 264   // padded bf16 row stride (528 B)

typedef __attribute__((ext_vector_type(8))) short bf16x8;
typedef __attribute__((ext_vector_type(4))) float f32x4;

__device__ inline unsigned short f2bf(float f) {
  union { float f; uint32_t u; } v; v.f = f;
  return (unsigned short)((v.u + 0x7fffu + ((v.u >> 16) & 1u)) >> 16);  // RNE
}
__device__ inline unsigned int pk2(float a, float b) {
  return (unsigned int)f2bf(a) | ((unsigned int)f2bf(b) << 16);
}
__device__ inline bf16x8 pack8(const float* g) {
  union { bf16x8 v; unsigned int u[4]; } c;
  c.u[0] = pk2(g[0], g[1]); c.u[1] = pk2(g[2], g[3]);
  c.u[2] = pk2(g[4], g[5]); c.u[3] = pk2(g[6], g[7]);
  return c.v;
}

// HW packed f32->bf16 (RNE, identical to f2bf for normal values). No builtin
// on gfx950 (m240) -> inline asm; non-volatile so scheduler can move/CSE it.
__device__ inline unsigned int pk2_hw(float a, float b) {
  unsigned int r;
  asm("v_cvt_pk_bf16_f32 %0, %1, %2" : "=v"(r) : "v"(a), "v"(b));
  return r;
}
__device__ inline unsigned short cvt1_hw(float a) {
  unsigned int r;
  asm("v_cvt_pk_bf16_f32 %0, %1, %1" : "=v"(r) : "v"(a));
  return (unsigned short)r;
}

// Pre-packed MFMA B-fragment layouts (bf16), built once per launch in d_ws:
//   W1F: [km:16][w:4][tn:4][lane:64][j:8]  -> 16384 slots * 16 B = 256 KiB
//   W2F: [ks:8][tn:4][lane:64][j:8]        ->  2048 slots * 16 B =  32 KiB
#define NSLOT1 (16 * 4 * 4 * 64)
#define NSLOT2 (8 * 4 * 64)
#define WS_NEEDED ((size_t)(NSLOT1 + NSLOT2) * 16)

__global__ __launch_bounds__(256) void prep_weights(
    const float* __restrict__ W1, const float* __restrict__ W2,
    unsigned short* __restrict__ w1f, unsigned short* __restrict__ w2f) {
  const int tid = blockIdx.x * 256 + threadIdx.x;
  if (tid < NSLOT1) {
    const int lane = tid & 63;
    const int quad = lane >> 4, l16 = lane & 15;
    int r = tid >> 6;
    const int tn = r & 3; r >>= 2;
    const int wv = r & 3; r >>= 2;
    const int km = r;  // 0..15
    const int kb = (km >> 3) * 256 + (km & 7) * 32 + quad * 8;
    const int n = wv * 64 + tn * 16 + l16;
    ushort4 lo, hi;
    lo.x = f2bf(W1[(size_t)(kb + 0) * NH + n]);
    lo.y = f2bf(W1[(size_t)(kb + 1) * NH + n]);
    lo.z = f2bf(W1[(size_t)(kb + 2) * NH + n]);
    lo.w = f2bf(W1[(size_t)(kb + 3) * NH + n]);
    hi.x = f2bf(W1[(size_t)(kb + 4) * NH + n]);
    hi.y = f2bf(W1[(size_t)(kb + 5) * NH + n]);
    hi.z = f2bf(W1[(size_t)(kb + 6) * NH + n]);
    hi.w = f2bf(W1[(size_t)(kb + 7) * NH + n]);
    *(ushort4*)&w1f[(size_t)tid * 8] = lo;
    *(ushort4*)&w1f[(size_t)tid * 8 + 4] = hi;
  } else if (tid < NSLOT1 + NSLOT2) {
    const int t2 = tid - NSLOT1;
    const int lane = t2 & 63;
    const int quad = lane >> 4, l16 = lane & 15;
    const int tn = (t2 >> 6) & 3;
    const int ks = t2 >> 8;  // 0..7
    const int kb = ks * 32 + quad * 8;
    const int n = tn * 16 + l16;
    ushort4 lo = {0, 0, 0, 0}, hi = {0, 0, 0, 0};
    if (n < NS) {
      lo.x = f2bf(W2[(size_t)(kb + 0) * NS + n]);
      lo.y = f2bf(W2[(size_t)(kb + 1) * NS + n]);
      lo.z = f2bf(W2[(size_t)(kb + 2) * NS + n]);
      lo.w = f2bf(W2[(size_t)(kb + 3) * NS + n]);
      hi.x = f2bf(W2[(size_t)(kb + 4) * NS + n]);
      hi.y = f2bf(W2[(size_t)(kb + 5) * NS + n]);
      hi.z = f2bf(W2[(size_t)(kb + 6) * NS + n]);
      hi.w = f2bf(W2[(size_t)(kb + 7) * NS + n]);
    }
    *(ushort4*)&w2f[(size_t)t2 * 8] = lo;
    *(ushort4*)&w2f[(size_t)t2 * 8 + 4] = hi;
  }
}

// ONE kernel, 256 threads (4 waves), 64-row geometry (R2 structure: proven
// 43 us/dispatch). R4 change: all hot-path f32->bf16 conversions use HW
// v_cvt_pk_bf16_f32 (1 op / 2 values vs ~4-5 ops/value bit-twiddle), and
// softmax divide -> v_rcp mul. Register-neutral: stays at 64 VGPR + 64 AGPR
// = 4 waves/SIMD with 4 blocks/CU (LDS 34816 B).
template <bool PACKED>
__global__ __launch_bounds__(256, 4) void fused_kernel(
    const float* __restrict__ E, const float* __restrict__ logits,
    const int* __restrict__ kw,
    const float* __restrict__ W1, const float* __restrict__ W2,
    const unsigned short* __restrict__ w1f, const unsigned short* __restrict__ w2f,
    const float* __restrict__ b1, const float* __restrict__ b2,
    float* __restrict__ out) {
  const int b = blockIdx.y;
  const int a0 = blockIdx.x * 63;   // first align t of this block
  const int base = a0 - 1;          // first trans row computed
  const int tid = threadIdx.x;
  const int w = tid >> 6;
  const int lane = tid & 63;
  const int quad = lane >> 4;
  const int l16 = lane & 15;
  const int n0 = w * 64;

  __shared__ unsigned short lds[65 * LDSROW];  // 34320 B: E-tile -> h -> U
  float* TRf = (float*)lds;                    // U[64][68] f32 (17408 B)

  const float* Eb = E + (size_t)b * NT * NH;
  const float* lb = logits + (size_t)b * NT * NS;

  // Stage E rows base..base+64 (clamped), f32 -> bf16 via v_cvt_pk.
  // Rows 0..63 in 16 unrolled iters (row = it*4 + w, coalesced 1KB/wave),
  // row 64 by wave 0.
  #pragma unroll
  for (int it = 0; it < 16; ++it) {
    const int row = it * 4 + w;
    int tr = base + row;
    tr = (tr < 0) ? 0 : (tr > NT - 1 ? NT - 1 : tr);
    float4 v = *(const float4*)&Eb[(size_t)tr * NH + (lane << 2)];
    uint2 o;
    o.x = pk2_hw(v.x, v.y); o.y = pk2_hw(v.z, v.w);
    *(uint2*)&lds[row * LDSROW + (lane << 2)] = o;
  }
  if (tid < 64) {
    int tr = base + 64; if (tr > NT - 1) tr = NT - 1;
    float4 v = *(const float4*)&Eb[(size_t)tr * NH + (lane << 2)];
    uint2 o;
    o.x = pk2_hw(v.x, v.y); o.y = pk2_hw(v.z, v.w);
    *(uint2*)&lds[64 * LDSROW + (lane << 2)] = o;
  }
  __syncthreads();

  // GEMM1: h[m][n] = e[base+m+1]@W1_top + e[base+m]@W1_bot  (m = 0..63,
  // wave w owns cols n0..n0+63)
  f32x4 acc[4][4];
  #pragma unroll
  for (int tm = 0; tm < 4; ++tm)
    #pragma unroll
    for (int tn = 0; tn < 4; ++tn) acc[tm][tn] = (f32x4){0.f, 0.f, 0.f, 0.f};

  if constexpr (PACKED) {
    // fragment (km,tn) lives at wbase + ((km<<4)+tn)*512 ushorts
    const unsigned short* wbase = w1f + (size_t)(((w << 2) * 64) + lane) * 8;
#define W1F_AT(KM, TN) \
  (*(const bf16x8*)(wbase + ((size_t)((((KM) << 4) + (TN))) << 9)))
    bf16x8 cb0 = W1F_AT(0, 0), cb1 = W1F_AT(0, 1);
    bf16x8 cb2 = W1F_AT(0, 2), cb3 = W1F_AT(0, 3);
    #pragma unroll
    for (int km = 0; km < 16; ++km) {
      bf16x8 nb0, nb1, nb2, nb3;
      if (km < 15) {  // one-ahead register double buffer (hides L2 latency)
        nb0 = W1F_AT(km + 1, 0); nb1 = W1F_AT(km + 1, 1);
        nb2 = W1F_AT(km + 1, 2); nb3 = W1F_AT(km + 1, 3);
      }
      const int aoff = (km >> 3) ? 0 : 1;  // top half pairs e[t+1]
      bf16x8 af[4];
      #pragma unroll
      for (int tm = 0; tm < 4; ++tm)
        af[tm] = *(const bf16x8*)&lds[(tm * 16 + l16 + aoff) * LDSROW +
                                      (km & 7) * 32 + quad * 8];
      #pragma unroll
      for (int tm = 0; tm < 4; ++tm)
        acc[tm][0] = __builtin_amdgcn_mfma_f32_16x16x32_bf16(af[tm], cb0, acc[tm][0], 0, 0, 0);
      #pragma unroll
      for (int tm = 0; tm < 4; ++tm)
        acc[tm][1] = __builtin_amdgcn_mfma_f32_16x16x32_bf16(af[tm], cb1, acc[tm][1], 0, 0, 0);
      #pragma unroll
      for (int tm = 0; tm < 4; ++tm)
        acc[tm][2] = __builtin_amdgcn_mfma_f32_16x16x32_bf16(af[tm], cb2, acc[tm][2], 0, 0, 0);
      #pragma unroll
      for (int tm = 0; tm < 4; ++tm)
        acc[tm][3] = __builtin_amdgcn_mfma_f32_16x16x32_bf16(af[tm], cb3, acc[tm][3], 0, 0, 0);
      if (km < 15) { cb0 = nb0; cb1 = nb1; cb2 = nb2; cb3 = nb3; }
    }
#undef W1F_AT
  } else {
    const float* w1p = W1 + (size_t)(quad * 8) * NH + n0 + l16;
    #pragma unroll
    for (int km = 0; km < 16; ++km) {
      const int hk = (km >> 3) * 256 + (km & 7) * 32;
      const int aoff = (km >> 3) ? 0 : 1;
      bf16x8 af[4];
      #pragma unroll
      for (int tm = 0; tm < 4; ++tm)
        af[tm] = *(const bf16x8*)&lds[(tm * 16 + l16 + aoff) * LDSROW +
                                      (km & 7) * 32 + quad * 8];
      float g[8], gn[8];
      #pragma unroll
      for (int j = 0; j < 8; ++j) g[j] = w1p[(size_t)(hk + j) * NH];
      #pragma unroll
      for (int tn = 0; tn < 4; ++tn) {
        if (tn < 3) {
          #pragma unroll
          for (int j = 0; j < 8; ++j)
            gn[j] = w1p[(size_t)(hk + j) * NH + (tn + 1) * 16];
        }
        bf16x8 bq = pack8(g);
        #pragma unroll
        for (int tm = 0; tm < 4; ++tm)
          acc[tm][tn] = __builtin_amdgcn_mfma_f32_16x16x32_bf16(
              af[tm], bq, acc[tm][tn], 0, 0, 0);
        if (tn < 3) {
          #pragma unroll
          for (int j = 0; j < 8; ++j) g[j] = gn[j];
        }
      }
    }
  }
  __syncthreads();  // GEMM1 A-reads done

  // h = relu(acc + b1) -> bf16 LDS rows 0..63 (HW cvt, 1 op/value)
  #pragma unroll
  for (int tn = 0; tn < 4; ++tn) {
    float b1v = b1[n0 + tn * 16 + l16];
    #pragma unroll
    for (int tm = 0; tm < 4; ++tm)
      #pragma unroll
      for (int r = 0; r < 4; ++r) {
        float hv = fmaxf(acc[tm][tn][r] + b1v, 0.f);
        lds[(tm * 16 + quad * 4 + r) * LDSROW + n0 + tn * 16 + l16] = cvt1_hw(hv);
      }
  }
  __syncthreads();

  // Prefetch logits values for this wave's U rows into registers (latency
  // hides under GEMM2). lpv[tn*4+r] pairs with acc2[tn][r].
  const int m0 = w * 16;
  float lpv[16];
  #pragma unroll
  for (int tn = 0; tn < 4; ++tn) {
    const int s = tn * 16 + l16;
    const int cc = (s < NS) ? s : NS - 1;
    #pragma unroll
    for (int r = 0; r < 4; ++r) {
      int tt = a0 + m0 + quad * 4 + r;
      if (tt > NT - 1) tt = NT - 1;
      lpv[tn * 4 + r] = lb[(size_t)tt * NS + cc];
    }
  }

  // GEMM2: wave w -> trans rows m0..m0+15
  f32x4 acc2[4];
  #pragma unroll
  for (int tn = 0; tn < 4; ++tn) acc2[tn] = (f32x4){0.f, 0.f, 0.f, 0.f};

  if constexpr (PACKED) {
    const unsigned short* w2base = w2f + (size_t)lane * 8;
    #pragma unroll
    for (int ks = 0; ks < 8; ++ks) {
      bf16x8 af = *(const bf16x8*)&lds[(m0 + l16) * LDSROW + ks * 32 + quad * 8];
      #pragma unroll
      for (int tn = 0; tn < 4; ++tn) {
        bf16x8 bq = *(const bf16x8*)(w2base + ((size_t)((ks << 2) + tn) << 9));
        acc2[tn] = __builtin_amdgcn_mfma_f32_16x16x32_bf16(af, bq, acc2[tn], 0, 0, 0);
      }
    }
  } else {
    #pragma unroll
    for (int ks = 0; ks < 8; ++ks) {
      const int k0 = ks * 32;
      bf16x8 af = *(const bf16x8*)&lds[(m0 + l16) * LDSROW + k0 + quad * 8];
      #pragma unroll
      for (int tn = 0; tn < 4; ++tn) {
        const int n = tn * 16 + l16;
        float g[8];
        #pragma unroll
        for (int j = 0; j < 8; ++j)
          g[j] = (n < NS) ? W2[(size_t)(k0 + quad * 8 + j) * NS + n] : 0.f;
        bf16x8 bq = pack8(g);
        acc2[tn] = __builtin_amdgcn_mfma_f32_16x16x32_bf16(af, bq, acc2[tn], 0, 0, 0);
      }
    }
  }
  __syncthreads();  // all h reads done; h region now reused for U

  // U[m][s] = trans[base+m][s] + b2[s] + logp-raw[a0+m][s]  (f32)
  #pragma unroll
  for (int tn = 0; tn < 4; ++tn) {
    const int s = tn * 16 + l16;
    const float b2v = (s < NS) ? b2[s] : 0.f;
    #pragma unroll
    for (int r = 0; r < 4; ++r)
      TRf[(m0 + quad * 4 + r) * 68 + s] = acc2[tn][r] + b2v + lpv[tn * 4 + r];
  }
  __syncthreads();

  // Softmax for t = a0 + j, j in [0, 62]: sc = U[j] + U[j+1] (interior)
  for (int rr = 0; rr < 16; ++rr) {
    const int j = m0 + rr;
    const int t = a0 + j;
    if (j == 63 || t > NT - 1) continue;
    float sc;
    if (t == 0) {
      float v = (lane < NS) ? lb[lane] : -1e30f;  // logits row 0 from global
      float m = v;
      #pragma unroll
      for (int o = 32; o > 0; o >>= 1) m = fmaxf(m, __shfl_xor(m, o));
      float ee = (lane < NS) ? __expf(v - m) : 0.f;
      float ss = ee;
      #pragma unroll
      for (int o = 32; o > 0; o >>= 1) ss += __shfl_xor(ss, o);
      const float lse = m + __logf(ss);
      const float f00 = lb[kw[b * 32]] - lse;
      sc = ((lane == 0) ? f00 : 0.f) + TRf[68 + lane];  // + U[1]
    } else if (t == NT - 1) {
      sc = TRf[j * 68 + lane];                          // U[j]
    } else {
      sc = TRf[j * 68 + lane] + TRf[(j + 1) * 68 + lane];
    }
    float e = (lane < NS) ? __expf(sc) : 0.f;
    float s = e;
    #pragma unroll
    for (int o = 32; o > 0; o >>= 1) s += __shfl_xor(s, o);
    const float sinv = __builtin_amdgcn_rcpf(s);  // ~1ulp, tol 4e-3 >> error
    if (lane < NS) out[((size_t)b * NT + t) * NS + lane] = e * sinv;
  }
}

extern "C" void kernel_launch(void* const* d_in, const int* in_sizes, int n_in,
                              void* d_out, int out_size, void* d_ws, size_t ws_size,
                              hipStream_t stream) {
  const float* logits = (const float*)d_in[0];
  const float* E      = (const float*)d_in[1];
  const int*   kw     = (const int*)d_in[2];
  const float* W1     = (const float*)d_in[3];
  const float* b1     = (const float*)d_in[4];
  const float* W2     = (const float*)d_in[5];
  const float* b2     = (const float*)d_in[6];
  float* out = (float*)d_out;

  dim3 g(32, NB);  // 32 t-blocks (63 t's each) x 32 batches = 1024 blocks

  if (ws_size >= WS_NEEDED && d_ws != nullptr) {
    unsigned short* w1f = (unsigned short*)d_ws;
    unsigned short* w2f = w1f + (size_t)NSLOT1 * 8;
    prep_weights<<<dim3((NSLOT1 + NSLOT2) / 256), 256, 0, stream>>>(W1, W2, w1f, w2f);
    fused_kernel<true><<<g, 256, 0, stream>>>(E, logits, kw, W1, W2, w1f, w2f,
                                              b1, b2, out);
  } else {
    fused_kernel<false><<<g, 256, 0, stream>>>(E, logits, kw, W1, W2, nullptr,
                                               nullptr, b1, b2, out);
  }
}